// Round 12
// baseline (1193.044 us; speedup 1.0000x reference)
//
#include <hip/hip_runtime.h>
#include <stdint.h>

#define NTOK 16384        // B*D*L = 8*16*128
#define HDIM 512
#define FDIM 4096
#define NHEAD 8

typedef __attribute__((ext_vector_type(8))) _Float16 f16x8;
typedef __attribute__((ext_vector_type(16))) float f32x16;
#define LOSCALE 4096.0f
#define LOINV   (1.0f / 4096.0f)

static __device__ __forceinline__ void ld8f(const float* p, float* v) {
    *(float4*)&v[0] = *(const float4*)p;
    *(float4*)&v[4] = *(const float4*)(p + 4);
}
static __device__ __forceinline__ void st8f(float* p, const float* v) {
    *(float4*)p       = *(const float4*)&v[0];
    *(float4*)(p + 4) = *(const float4*)&v[4];
}

// ---- x0 = concat(query_token, zL[:, :-1]) -> f32 ----
__global__ __launch_bounds__(256) void build_x_k(const float* __restrict__ zL,
                                                 const float* __restrict__ qt,
                                                 float* __restrict__ X) {
    int idx = blockIdx.x * 256 + threadIdx.x;
    int n = idx >> 6;
    int h = (idx & 63) << 3;
    int d = (n >> 7) & 15;
    const float* src = d ? (zL + (((size_t)(n - 128)) << 9) + h) : (qt + h);
    float v[8];
    ld8f(src, v);
    st8f(X + (((size_t)n) << 9) + h, v);
}

// ---- per-row LN stats (mu, rstd); one wave per row ----
__global__ __launch_bounds__(256) void ln_stats_k(const float* __restrict__ X,
                                                  float* __restrict__ mu,
                                                  float* __restrict__ rstd) {
    int row = blockIdx.x * 4 + (threadIdx.x >> 6);
    int lane = threadIdx.x & 63;
    const float* xr = X + (((size_t)row) << 9) + (lane << 3);
    float v[8];
    ld8f(xr, v);
    float s = 0.f;
#pragma unroll
    for (int i = 0; i < 8; ++i) s += v[i];
#pragma unroll
    for (int off = 32; off; off >>= 1) s += __shfl_xor(s, off);
    float m = s * (1.0f / 512.0f);
    float q = 0.f;
#pragma unroll
    for (int i = 0; i < 8; ++i) { float d = v[i] - m; q += d * d; }
#pragma unroll
    for (int off = 32; off; off >>= 1) q += __shfl_xor(q, off);
    if (lane == 0) {
        mu[row] = m;
        rstd[row] = 1.0f / sqrtf(q * (1.0f / 512.0f) + 1e-5f);
    }
}

// ---- f32 NT GEMM (fallback path only) --------------------------------------
template<bool LN, bool ADD_C, bool BIAS>
__global__ __launch_bounds__(256) void gemm_k(const float* __restrict__ A,
                                              const float* __restrict__ W,
                                              float* __restrict__ C,
                                              const float* __restrict__ mu,
                                              const float* __restrict__ rstd,
                                              const float* __restrict__ gamma,
                                              const float* __restrict__ beta,
                                              const float* __restrict__ bias,
                                              int M, int N, int K) {
    __shared__ float As[16][128];
    __shared__ float Bs[16][128];
    const int tid = threadIdx.x;
    const int bm = blockIdx.y << 7;
    const int bn = blockIdx.x << 7;
    const int tx = tid & 15, ty = tid >> 4;
    const int lr = tid >> 1;
    const int lk = (tid & 1) << 3;
    const float* Ap = A + (size_t)(bm + lr) * K + lk;
    const float* Wp = W + (size_t)(bn + lr) * K + lk;
    float mu_r = 0.f, rs_r = 0.f;
    if (LN) { mu_r = mu[bm + lr]; rs_r = rstd[bm + lr]; }
    float acc[8][8];
#pragma unroll
    for (int i = 0; i < 8; ++i)
#pragma unroll
        for (int j = 0; j < 8; ++j) acc[i][j] = 0.f;

    float av[8], bv[8];
    ld8f(Ap, av);
    ld8f(Wp, bv);
    if (LN) {
        float gv[8], be[8];
        ld8f(gamma + lk, gv);
        ld8f(beta + lk, be);
#pragma unroll
        for (int i = 0; i < 8; ++i) av[i] = (av[i] - mu_r) * rs_r * gv[i] + be[i];
    }
    const int nIt = K >> 4;
    for (int it = 0; it < nIt; ++it) {
        __syncthreads();
#pragma unroll
        for (int i = 0; i < 8; ++i) { As[lk + i][lr] = av[i]; Bs[lk + i][lr] = bv[i]; }
        __syncthreads();
        if (it + 1 < nIt) {
            const int k0 = (it + 1) << 4;
            ld8f(Ap + k0, av);
            ld8f(Wp + k0, bv);
            if (LN) {
                float gv[8], be[8];
                ld8f(gamma + k0 + lk, gv);
                ld8f(beta + k0 + lk, be);
#pragma unroll
                for (int i = 0; i < 8; ++i) av[i] = (av[i] - mu_r) * rs_r * gv[i] + be[i];
            }
        }
#pragma unroll
        for (int kk = 0; kk < 16; ++kk) {
            float a[8], b[8];
            *(float4*)&a[0] = *(const float4*)&As[kk][ty << 3];
            *(float4*)&a[4] = *(const float4*)&As[kk][(ty << 3) + 4];
            *(float4*)&b[0] = *(const float4*)&Bs[kk][tx << 3];
            *(float4*)&b[4] = *(const float4*)&Bs[kk][(tx << 3) + 4];
#pragma unroll
            for (int i = 0; i < 8; ++i)
#pragma unroll
                for (int j = 0; j < 8; ++j)
                    acc[i][j] = fmaf(a[i], b[j], acc[i][j]);
        }
    }
    const int orow = bm + (ty << 3);
    const int ocol = bn + (tx << 3);
    float badd[8];
    if (BIAS) ld8f(bias + ocol, badd);
#pragma unroll
    for (int i = 0; i < 8; ++i) {
        float* cp = C + (size_t)(orow + i) * N + ocol;
        float o[8];
#pragma unroll
        for (int j = 0; j < 8; ++j) o[j] = acc[i][j];
        if (BIAS) {
#pragma unroll
            for (int j = 0; j < 8; ++j) o[j] += badd[j];
        }
        if (ADD_C) {
            float4 c0 = *(const float4*)cp;
            float4 c1 = *(const float4*)(cp + 4);
            o[0] += c0.x; o[1] += c0.y; o[2] += c0.z; o[3] += c0.w;
            o[4] += c1.x; o[5] += c1.y; o[6] += c1.z; o[7] += c1.w;
        }
        *(float4*)cp       = make_float4(o[0], o[1], o[2], o[3]);
        *(float4*)(cp + 4) = make_float4(o[4], o[5], o[6], o[7]);
    }
}

// ---- non-causal attention over L; 512 threads: 4 lanes per q-row (d-split) --
__global__ __launch_bounds__(512) void attn_l_k(float* __restrict__ QO,
                                                const float* __restrict__ K,
                                                const float* __restrict__ V) {
    __shared__ float ks[128][64];
    __shared__ float vs[128][64];
    const int seq = blockIdx.x, head = blockIdx.y;
    const int t = threadIdx.x;
    const size_t base = (((size_t)seq) << 16) + (head << 6);
#pragma unroll
    for (int i = 0; i < 4; ++i) {
        int slot = t + (i << 9);
        int row = slot >> 4;
        int c4 = (slot & 15) << 2;
        size_t g = base + (((size_t)row) << 9) + c4;
        *(float4*)&ks[row][c4] = *(const float4*)(K + g);
        *(float4*)&vs[row][c4] = *(const float4*)(V + g);
    }
    __syncthreads();
    const int r = t >> 2;
    const int q16 = (t & 3) << 4;
    float* qp = QO + base + (((size_t)r) << 9) + q16;
    float qr[16];
#pragma unroll
    for (int i = 0; i < 4; ++i) *(float4*)&qr[i << 2] = *(const float4*)(qp + (i << 2));
    float o[16];
#pragma unroll
    for (int d = 0; d < 16; ++d) o[d] = 0.f;
    float m = -1e30f, l = 0.f;
    for (int j = 0; j < 128; ++j) {
        const float* kp = &ks[j][q16];
        float s0 = 0.f, s1 = 0.f, s2 = 0.f, s3 = 0.f;
#pragma unroll
        for (int d = 0; d < 16; d += 4) {
            s0 = fmaf(qr[d + 0], kp[d + 0], s0);
            s1 = fmaf(qr[d + 1], kp[d + 1], s1);
            s2 = fmaf(qr[d + 2], kp[d + 2], s2);
            s3 = fmaf(qr[d + 3], kp[d + 3], s3);
        }
        float sp = (s0 + s1) + (s2 + s3);
        sp += __shfl_xor(sp, 1);
        sp += __shfl_xor(sp, 2);
        float s = sp * 0.125f;
        if (s > m) {
            float c = expf(m - s);
#pragma unroll
            for (int d = 0; d < 16; ++d) o[d] *= c;
            l *= c;
            m = s;
        }
        float w = expf(s - m);
        l += w;
        const float* vp = &vs[j][q16];
#pragma unroll
        for (int d = 0; d < 16; ++d) o[d] = fmaf(w, vp[d], o[d]);
    }
    float inv = 1.0f / l;
#pragma unroll
    for (int i = 0; i < 4; ++i)
        *(float4*)(qp + (i << 2)) = make_float4(o[i * 4] * inv, o[i * 4 + 1] * inv,
                                                o[i * 4 + 2] * inv, o[i * 4 + 3] * inv);
}

// ---- causal attention over D (1024 seqs of len 16); O over Q ----
__global__ __launch_bounds__(128) void attn_d_k(float* __restrict__ QO,
                                                const float* __restrict__ K,
                                                const float* __restrict__ V) {
    __shared__ float ks[16][512];
    __shared__ float vs[16][512];
    const int bl = blockIdx.x;
    const int b = bl >> 7, l = bl & 127;
    const int t = threadIdx.x;
    const size_t base = ((size_t)(b * 2048 + l)) << 9;
#pragma unroll
    for (int i = 0; i < 16; ++i) {
        int slot = t + (i << 7);
        int row = slot >> 7;
        int c4 = (slot & 127) << 2;
        size_t g = base + (((size_t)row) << 16) + c4;
        *(float4*)&ks[row][c4] = *(const float4*)(K + g);
        *(float4*)&vs[row][c4] = *(const float4*)(V + g);
    }
    __syncthreads();
    const int head = t >> 4, dr = t & 15;
    const int ho = head << 6;
    float qr[64];
    float* qp = QO + base + (((size_t)dr) << 16) + ho;
#pragma unroll
    for (int i = 0; i < 16; ++i) *(float4*)&qr[i << 2] = *(const float4*)(qp + (i << 2));
    float s[16];
    float m = -1e30f;
#pragma unroll
    for (int j = 0; j < 16; ++j) {
        float s0 = 0.f, s1 = 0.f, s2 = 0.f, s3 = 0.f;
#pragma unroll
        for (int d = 0; d < 64; d += 4) {
            s0 = fmaf(qr[d + 0], ks[j][ho + d + 0], s0);
            s1 = fmaf(qr[d + 1], ks[j][ho + d + 1], s1);
            s2 = fmaf(qr[d + 2], ks[j][ho + d + 2], s2);
            s3 = fmaf(qr[d + 3], ks[j][ho + d + 3], s3);
        }
        float sv = ((s0 + s1) + (s2 + s3)) * 0.125f;
        s[j] = (j <= dr) ? sv : -1e30f;
        m = fmaxf(m, s[j]);
    }
    float lsum = 0.f;
#pragma unroll
    for (int j = 0; j < 16; ++j) {
        float w = (j <= dr) ? expf(s[j] - m) : 0.f;
        s[j] = w;
        lsum += w;
    }
    float inv = 1.0f / lsum;
    float o[64];
#pragma unroll
    for (int d = 0; d < 64; ++d) o[d] = 0.f;
#pragma unroll
    for (int j = 0; j < 16; ++j) {
        float w = s[j];
#pragma unroll
        for (int d = 0; d < 64; ++d) o[d] = fmaf(w, vs[j][ho + d], o[d]);
    }
#pragma unroll
    for (int i = 0; i < 16; ++i)
        *(float4*)(qp + (i << 2)) = make_float4(o[i * 4] * inv, o[i * 4 + 1] * inv,
                                                o[i * 4 + 2] * inv, o[i * 4 + 3] * inv);
}

// ---- x_prior copy to output region (fallback path) ----
__global__ __launch_bounds__(256) void cast_out_k(const float* __restrict__ X,
                                                  float* __restrict__ out) {
    int idx = blockIdx.x * 256 + threadIdx.x;
    float v[8];
    ld8f(X + (((size_t)idx) << 3), v);
    st8f(out + (((size_t)idx) << 3), v);
}

// ---- x_src = zL - x_prior - bias_pre, in place over X (fallback path) ----
__global__ __launch_bounds__(256) void xsrc_k(const float* __restrict__ zL,
                                              const float* __restrict__ bias_pre,
                                              float* __restrict__ X) {
    int idx = blockIdx.x * 256 + threadIdx.x;
    int h = (idx & 63) << 3;
    float z[8], p[8], x[8];
    ld8f(zL + (((size_t)idx) << 3), z);
    ld8f(bias_pre + h, p);
    float* xp = X + (((size_t)idx) << 3);
    ld8f(xp, x);
    float o[8];
#pragma unroll
    for (int i = 0; i < 8; ++i) o[i] = z[i] - x[i] - p[i];
    st8f(xp, o);
}

// ---- fused: out_xp = x; x_src(in place) = zL - x - bias_pre ----
__global__ __launch_bounds__(256) void xprior_xsrc_k(const float* __restrict__ zL,
                                                     const float* __restrict__ bias_pre,
                                                     float* __restrict__ X,
                                                     float* __restrict__ out_xp) {
    int idx = blockIdx.x * 256 + threadIdx.x;
    int h = (idx & 63) << 3;
    float z[8], p[8], x[8];
    ld8f(zL + (((size_t)idx) << 3), z);
    ld8f(bias_pre + h, p);
    float* xp = X + (((size_t)idx) << 3);
    ld8f(xp, x);
    st8f(out_xp + (((size_t)idx) << 3), x);
    float o[8];
#pragma unroll
    for (int i = 0; i < 8; ++i) o[i] = z[i] - x[i] - p[i];
    st8f(xp, o);
}

// ---- 2-way fp16 scaled split: x = h + l*2^-12 ----
__global__ __launch_bounds__(256) void split2_k(const float* __restrict__ in,
                                                _Float16* __restrict__ ph,
                                                _Float16* __restrict__ pl) {
    int idx = blockIdx.x * 256 + threadIdx.x;
    float v[8];
    ld8f(in + (((size_t)idx) << 3), v);
    _Float16 h8[8], l8[8];
#pragma unroll
    for (int i = 0; i < 8; ++i) {
        _Float16 h = (_Float16)v[i];
        float r = v[i] - (float)h;          // exact
        h8[i] = h;
        l8[i] = (_Float16)(r * LOSCALE);
    }
    *(int4*)(ph + (((size_t)idx) << 3)) = *(int4*)h8;
    *(int4*)(pl + (((size_t)idx) << 3)) = *(int4*)l8;
}

// ---- fused LN + 2-way fp16 scaled split ----
__global__ __launch_bounds__(256) void split2_ln_k(const float* __restrict__ X,
                                                   const float* __restrict__ mu,
                                                   const float* __restrict__ rstd,
                                                   const float* __restrict__ gamma,
                                                   const float* __restrict__ beta,
                                                   _Float16* __restrict__ ph,
                                                   _Float16* __restrict__ pl) {
    int idx = blockIdx.x * 256 + threadIdx.x;
    int row = idx >> 6;
    int h = (idx & 63) << 3;
    float v[8], gv[8], be[8];
    ld8f(X + (((size_t)idx) << 3), v);
    ld8f(gamma + h, gv);
    ld8f(beta + h, be);
    float m = mu[row], rs = rstd[row];
    _Float16 h8[8], l8[8];
#pragma unroll
    for (int i = 0; i < 8; ++i) {
        float y = (v[i] - m) * rs * gv[i] + be[i];
        _Float16 hh = (_Float16)y;
        float r = y - (float)hh;
        h8[i] = hh;
        l8[i] = (_Float16)(r * LOSCALE);
    }
    *(int4*)(ph + (((size_t)idx) << 3)) = *(int4*)h8;
    *(int4*)(pl + (((size_t)idx) << 3)) = *(int4*)l8;
}

// ---- 3-pass split-fp16 MFMA NT GEMM, 32x32x16 ------------------------------
// LDT=34 halves: 17-dword row stride (odd) -> per-lane start bank is a
// permutation of 0..31 for row-strided b128/b64 reads => conflict-free.
// SWZ=1: 1D grid, XCD-clustered (bn = (id&7)*4 + (id>>3)&3, bm = id>>5) so
// each XCD keeps 4 dict column-panels (1 MB) L2-resident.
#define LDT 34
template<int SWZ, bool ADD_C, bool BIAS>
__global__ __launch_bounds__(256) void gemm_f16_k(
        const _Float16* __restrict__ Xh, const _Float16* __restrict__ Xl,
        const _Float16* __restrict__ Wh, const _Float16* __restrict__ Wl,
        const float* __restrict__ bias, float* __restrict__ Cout, int ldc) {
    __shared__ _Float16 Ah[128][LDT], Al[128][LDT];
    __shared__ _Float16 Bh[128][LDT], Bl[128][LDT];
    const int tid = threadIdx.x;
    int bm, bn;
    if (SWZ) {
        int id = blockIdx.x;
        bn = (((id & 7) << 2) + ((id >> 3) & 3)) << 7;
        bm = (id >> 5) << 7;
    } else {
        bm = blockIdx.y << 7;
        bn = blockIdx.x << 7;
    }
    const int w = tid >> 6, lane = tid & 63;
    const int wr = w >> 1, wc = w & 1;
    const int l31 = lane & 31, hh = lane >> 5;
    f32x16 acc1[2][2], acc2[2][2];
#pragma unroll
    for (int i = 0; i < 2; ++i)
#pragma unroll
        for (int j = 0; j < 2; ++j)
#pragma unroll
            for (int r = 0; r < 16; ++r) { acc1[i][j][r] = 0.f; acc2[i][j][r] = 0.f; }

    for (int k0 = 0; k0 < HDIM; k0 += 32) {
        __syncthreads();
#pragma unroll
        for (int i = 0; i < 2; ++i) {
            int s = tid + (i << 8);
            int row = s >> 2, kg = (s & 3) << 3;
            size_t ga = (size_t)(bm + row) * HDIM + k0 + kg;
            size_t gb = (size_t)(bn + row) * HDIM + k0 + kg;
            *(int4*)&Ah[row][kg] = *(const int4*)(Xh + ga);
            *(int4*)&Al[row][kg] = *(const int4*)(Xl + ga);
            *(int4*)&Bh[row][kg] = *(const int4*)(Wh + gb);
            *(int4*)&Bl[row][kg] = *(const int4*)(Wl + gb);
        }
        __syncthreads();
#pragma unroll
        for (int kh = 0; kh < 2; ++kh) {
            const int ko = (kh << 4) + (hh << 3);   // k offset (halves)
            f16x8 fah[2], fal[2];
#pragma unroll
            for (int mf = 0; mf < 2; ++mf) {
                int ar = (wr << 6) + (mf << 5) + l31;
                fah[mf] = *(const f16x8*)&Ah[ar][ko];
                fal[mf] = *(const f16x8*)&Al[ar][ko];
            }
#pragma unroll
            for (int nf = 0; nf < 2; ++nf) {
                int bc_ = (wc << 6) + (nf << 5) + l31;
                f16x8 bh = *(const f16x8*)&Bh[bc_][ko];
                f16x8 bl = *(const f16x8*)&Bl[bc_][ko];
#pragma unroll
                for (int mf = 0; mf < 2; ++mf) {
                    acc1[mf][nf] = __builtin_amdgcn_mfma_f32_32x32x16_f16(fah[mf], bh, acc1[mf][nf], 0, 0, 0);
                    acc2[mf][nf] = __builtin_amdgcn_mfma_f32_32x32x16_f16(fah[mf], bl, acc2[mf][nf], 0, 0, 0);
                    acc2[mf][nf] = __builtin_amdgcn_mfma_f32_32x32x16_f16(fal[mf], bh, acc2[mf][nf], 0, 0, 0);
                }
            }
        }
    }
#pragma unroll
    for (int mf = 0; mf < 2; ++mf)
#pragma unroll
        for (int nf = 0; nf < 2; ++nf) {
            int col = bn + (wc << 6) + (nf << 5) + l31;
            float badd = BIAS ? bias[col] : 0.f;
#pragma unroll
            for (int r = 0; r < 16; ++r) {
                int row = bm + (wr << 6) + (mf << 5) + (r & 3) + ((r >> 2) << 3) + (hh << 2);
                float* cp = Cout + (size_t)row * ldc + col;
                float val = acc1[mf][nf][r] + acc2[mf][nf][r] * LOINV + badd;
                if (ADD_C) val += *cp;
                *cp = val;
            }
        }
}

// ---- per-row top-64: relu + exact radix select (early-exit) + scatter ----
__global__ __launch_bounds__(256) void topk_k(const float* __restrict__ logits,
                                              float* __restrict__ out) {
    const int row = blockIdx.x;
    const float* lr = logits + (((size_t)row) << 12);
    const int t = threadIdx.x;
    float v[16]; uint32_t u[16];
#pragma unroll
    for (int i = 0; i < 16; ++i) {
        float x = fmaxf(lr[t + (i << 8)], 0.f);
        v[i] = x;
        u[i] = __float_as_uint(x);
    }
    __shared__ int red[4];
    __shared__ unsigned long long bits[64];
    __shared__ int s_cut;
    uint32_t prefix = 0;
    bool exact = false;
    for (int bit = 30; bit >= 0; --bit) {
        uint32_t c = prefix | (1u << bit);
        int cnt = 0;
#pragma unroll
        for (int i = 0; i < 16; ++i) cnt += (u[i] >= c) ? 1 : 0;
#pragma unroll
        for (int off = 32; off; off >>= 1) cnt += __shfl_xor(cnt, off);
        if ((t & 63) == 0) red[t >> 6] = cnt;
        __syncthreads();
        int total = red[0] + red[1] + red[2] + red[3];
        __syncthreads();
        if (total >= 64) prefix = c;
        if (total == 64) { exact = true; break; }   // block-uniform
    }
    float* orow = out + (((size_t)row) << 12);
    if (exact) {
#pragma unroll
        for (int i = 0; i < 16; ++i) {
            int col = t + (i << 8);
            orow[col] = (u[i] >= prefix) ? v[i] : 0.f;
        }
        return;
    }
    const uint32_t T64 = prefix;
    int cg = 0;
#pragma unroll
    for (int i = 0; i < 16; ++i) cg += (u[i] > T64) ? 1 : 0;
#pragma unroll
    for (int off = 32; off; off >>= 1) cg += __shfl_xor(cg, off);
    if ((t & 63) == 0) red[t >> 6] = cg;
    __syncthreads();
    const int ngt = red[0] + red[1] + red[2] + red[3];
    int cut = -1;
    if (T64 != 0u) {
        const int r = 64 - ngt;
        if (t < 64) bits[t] = 0ull;
        __syncthreads();
#pragma unroll
        for (int i = 0; i < 16; ++i) {
            if (u[i] == T64) {
                int col = t + (i << 8);
                atomicOr(&bits[col >> 6], 1ull << (col & 63));
            }
        }
        __syncthreads();
        if (t == 0) {
            int need = r, cs = FDIM - 1;
            for (int wd = 0; wd < 64; ++wd) {
                int pc = __popcll(bits[wd]);
                if (need <= pc) {
                    unsigned long long bb = bits[wd];
                    for (int q = 1; q < need; ++q) bb &= bb - 1;
                    cs = (wd << 6) + (__ffsll(bb) - 1);
                    break;
                }
                need -= pc;
            }
            s_cut = cs;
        }
        __syncthreads();
        cut = s_cut;
    }
#pragma unroll
    for (int i = 0; i < 16; ++i) {
        int col = t + (i << 8);
        bool keep = (u[i] > T64) || (T64 != 0u && u[i] == T64 && col <= cut);
        orow[col] = keep ? v[i] : 0.f;
    }
}

extern "C" void kernel_launch(void* const* d_in, const int* in_sizes, int n_in,
                              void* d_out, int out_size, void* d_ws, size_t ws_size,
                              hipStream_t stream) {
    const float* zL      = (const float*)d_in[0];
    const float* gamma_l = (const float*)d_in[5];
    const float* beta_l  = (const float*)d_in[6];
    const float* gamma_d = (const float*)d_in[11];
    const float* beta_d  = (const float*)d_in[12];
    const float* dict_e  = (const float*)d_in[13];
    const float* bias_pre= (const float*)d_in[14];
    const float* bias_enc= (const float*)d_in[15];
    const float* qt      = (const float*)d_in[16];
    const float* wproj[8] = { (const float*)d_in[1], (const float*)d_in[2],
                              (const float*)d_in[3], (const float*)d_in[4],
                              (const float*)d_in[7], (const float*)d_in[8],
                              (const float*)d_in[9], (const float*)d_in[10] };

    float* out_z  = (float*)d_out;
    float* out_xp = out_z + (size_t)NTOK * FDIM;

    const size_t NHf = (size_t)NTOK * HDIM;
    float* B0 = (float*)d_out;         // residual X -> x_prior -> x_src
    float* B1 = B0 + NHf;              // Q / attn out
    float* B2 = B1 + NHf;              // K
    float* B3 = B2 + NHf;              // V

    float* wsf    = (float*)d_ws;
    float* mu     = wsf + 64;
    float* rstd   = mu + NTOK;
    float* logits = rstd + NTOK;       // crows*4096 f32

    const size_t dictE = (size_t)FDIM * HDIM;   // 2.1M
    const size_t WE    = (size_t)HDIM * HDIM;   // 262144

    int crows = NTOK;                  // single dict dispatch if ws allows
    const size_t mfmaFixedB = (64 + 2 * (size_t)NTOK) * sizeof(float)
                            + (2 * dictE + 16 * WE + 2 * NHf) * sizeof(_Float16);
    while (crows > 128 &&
           mfmaFixedB + (size_t)crows * FDIM * sizeof(float) > ws_size) crows >>= 1;
    const bool use_mfma_proj =
        mfmaFixedB + (size_t)crows * FDIM * sizeof(float) <= ws_size;

    const dim3 blk256(256), blk128(128), blk512(512);
    const dim3 gElem(4096);                      // NTOK*512/8/256
    const dim3 gProjM(HDIM / 128, NTOK / 128);   // (4, 128)

    if (use_mfma_proj) {
        _Float16* dh = (_Float16*)(logits + (size_t)crows * FDIM);
        _Float16* dl = dh + dictE;
        _Float16* wsp = dh + 2 * dictE;          // 8 weights x 2 splits x WE
        _Float16* xh = wsp + 16 * WE;
        _Float16* xl = xh + NHf;
        _Float16* wh[8], *wl[8];
        for (int i = 0; i < 8; ++i) {
            wh[i] = wsp + (size_t)i * 2 * WE;
            wl[i] = wh[i] + WE;
        }

        for (int i = 0; i < 8; ++i)
            split2_k<<<dim3(WE / 8 / 256), blk256, 0, stream>>>(wproj[i], wh[i], wl[i]);
        split2_k<<<dim3(dictE / 8 / 256), blk256, 0, stream>>>(dict_e, dh, dl);

        build_x_k<<<gElem, blk256, 0, stream>>>(zL, qt, B0);

        // ---- layer attention block ----
        ln_stats_k<<<dim3(NTOK / 4), blk256, 0, stream>>>(B0, mu, rstd);
        split2_ln_k<<<gElem, blk256, 0, stream>>>(B0, mu, rstd, gamma_l, beta_l, xh, xl);
        gemm_f16_k<0, false, false><<<gProjM, blk256, 0, stream>>>(xh, xl, wh[0], wl[0], nullptr, B1, HDIM);
        gemm_f16_k<0, false, false><<<gProjM, blk256, 0, stream>>>(xh, xl, wh[1], wl[1], nullptr, B2, HDIM);
        gemm_f16_k<0, false, false><<<gProjM, blk256, 0, stream>>>(xh, xl, wh[2], wl[2], nullptr, B3, HDIM);
        attn_l_k<<<dim3(128, NHEAD), blk512, 0, stream>>>(B1, B2, B3);
        split2_k<<<gElem, blk256, 0, stream>>>(B1, xh, xl);
        gemm_f16_k<0, true, false><<<gProjM, blk256, 0, stream>>>(xh, xl, wh[3], wl[3], nullptr, B0, HDIM);

        // ---- depth attention block ----
        ln_stats_k<<<dim3(NTOK / 4), blk256, 0, stream>>>(B0, mu, rstd);
        split2_ln_k<<<gElem, blk256, 0, stream>>>(B0, mu, rstd, gamma_d, beta_d, xh, xl);
        gemm_f16_k<0, false, false><<<gProjM, blk256, 0, stream>>>(xh, xl, wh[4], wl[4], nullptr, B1, HDIM);
        gemm_f16_k<0, false, false><<<gProjM, blk256, 0, stream>>>(xh, xl, wh[5], wl[5], nullptr, B2, HDIM);
        gemm_f16_k<0, false, false><<<gProjM, blk256, 0, stream>>>(xh, xl, wh[6], wl[6], nullptr, B3, HDIM);
        attn_d_k<<<dim3(1024), blk128, 0, stream>>>(B1, B2, B3);
        split2_k<<<gElem, blk256, 0, stream>>>(B1, xh, xl);
        gemm_f16_k<0, true, false><<<gProjM, blk256, 0, stream>>>(xh, xl, wh[7], wl[7], nullptr, B0, HDIM);

        // ---- x_prior out + x_src + one-shot split ----
        xprior_xsrc_k<<<gElem, blk256, 0, stream>>>(zL, bias_pre, B0, out_xp);
        split2_k<<<gElem, blk256, 0, stream>>>(B0, xh, xl);

        if (crows == NTOK) {
            // single dict GEMM, XCD-clustered 1D grid (4096 blocks)
            gemm_f16_k<1, false, true><<<dim3(4096), blk256, 0, stream>>>(
                xh, xl, dh, dl, bias_enc, logits, FDIM);
            topk_k<<<dim3(NTOK), blk256, 0, stream>>>(logits, out_z);
        } else {
            const dim3 gDict(FDIM / 128, crows / 128);
            for (int c0 = 0; c0 < NTOK; c0 += crows) {
                gemm_f16_k<0, false, true><<<gDict, blk256, 0, stream>>>(
                    xh + (size_t)c0 * HDIM, xl + (size_t)c0 * HDIM,
                    dh, dl, bias_enc, logits, FDIM);
                topk_k<<<dim3(crows), blk256, 0, stream>>>(logits, out_z + (size_t)c0 * FDIM);
            }
        }
    } else {
        // ---- fallback: f32 projections, per-chunk fp16 splits ----
        int cr = 2048;
        const size_t fixedB = (64 + 2 * (size_t)NTOK) * sizeof(float) + dictE * 2 * sizeof(_Float16);
        while (cr > 128 &&
               fixedB + (size_t)cr * FDIM * sizeof(float) + (size_t)cr * HDIM * 2 * sizeof(_Float16) > ws_size)
            cr >>= 1;
        _Float16* dh = (_Float16*)(logits + (size_t)cr * FDIM);
        _Float16* dl = dh + dictE;
        _Float16* xh = dl + dictE;
        _Float16* xl = xh + (size_t)cr * HDIM;

        build_x_k<<<gElem, blk256, 0, stream>>>(zL, qt, B0);
        ln_stats_k<<<dim3(NTOK / 4), blk256, 0, stream>>>(B0, mu, rstd);
        gemm_k<true,  false, false><<<gProjM, blk256, 0, stream>>>(B0, wproj[0], B1, mu, rstd, gamma_l, beta_l, nullptr, NTOK, HDIM, HDIM);
        gemm_k<true,  false, false><<<gProjM, blk256, 0, stream>>>(B0, wproj[1], B2, mu, rstd, gamma_l, beta_l, nullptr, NTOK, HDIM, HDIM);
        gemm_k<true,  false, false><<<gProjM, blk256, 0, stream>>>(B0, wproj[2], B3, mu, rstd, gamma_l, beta_l, nullptr, NTOK, HDIM, HDIM);
        attn_l_k<<<dim3(128, NHEAD), blk512, 0, stream>>>(B1, B2, B3);
        gemm_k<false, true,  false><<<gProjM, blk256, 0, stream>>>(B1, wproj[3], B0, nullptr, nullptr, nullptr, nullptr, nullptr, NTOK, HDIM, HDIM);
        ln_stats_k<<<dim3(NTOK / 4), blk256, 0, stream>>>(B0, mu, rstd);
        gemm_k<true,  false, false><<<gProjM, blk256, 0, stream>>>(B0, wproj[4], B1, mu, rstd, gamma_d, beta_d, nullptr, NTOK, HDIM, HDIM);
        gemm_k<true,  false, false><<<gProjM, blk256, 0, stream>>>(B0, wproj[5], B2, mu, rstd, gamma_d, beta_d, nullptr, NTOK, HDIM, HDIM);
        gemm_k<true,  false, false><<<gProjM, blk256, 0, stream>>>(B0, wproj[6], B3, mu, rstd, gamma_d, beta_d, nullptr, NTOK, HDIM, HDIM);
        attn_d_k<<<dim3(1024), blk128, 0, stream>>>(B1, B2, B3);
        gemm_k<false, true,  false><<<gProjM, blk256, 0, stream>>>(B1, wproj[7], B0, nullptr, nullptr, nullptr, nullptr, nullptr, NTOK, HDIM, HDIM);
        cast_out_k<<<gElem, blk256, 0, stream>>>(B0, out_xp);
        xsrc_k<<<gElem, blk256, 0, stream>>>(zL, bias_pre, B0);
        split2_k<<<dim3(dictE / 8 / 256), blk256, 0, stream>>>(dict_e, dh, dl);
        const dim3 gDict(FDIM / 128, cr / 128);
        for (int c0 = NTOK - cr; c0 >= 0; c0 -= cr) {
            split2_k<<<dim3(cr * HDIM / 8 / 256), blk256, 0, stream>>>(B0 + (size_t)c0 * HDIM, xh, xl);
            gemm_f16_k<0, false, true><<<gDict, blk256, 0, stream>>>(xh, xl, dh, dl, bias_enc, logits, FDIM);
            topk_k<<<dim3(cr), blk256, 0, stream>>>(logits, out_z + (size_t)c0 * FDIM);
        }
    }
}

// Round 13
// 1168.084 us; speedup vs baseline: 1.0214x; 1.0214x over previous
//
#include <hip/hip_runtime.h>
#include <stdint.h>

#define NTOK 16384        // B*D*L = 8*16*128
#define HDIM 512
#define FDIM 4096
#define NHEAD 8

typedef __attribute__((ext_vector_type(8))) _Float16 f16x8;
typedef __attribute__((ext_vector_type(16))) float f32x16;
#define LOSCALE 4096.0f
#define LOINV   (1.0f / 4096.0f)

static __device__ __forceinline__ void ld8f(const float* p, float* v) {
    *(float4*)&v[0] = *(const float4*)p;
    *(float4*)&v[4] = *(const float4*)(p + 4);
}
static __device__ __forceinline__ void st8f(float* p, const float* v) {
    *(float4*)p       = *(const float4*)&v[0];
    *(float4*)(p + 4) = *(const float4*)&v[4];
}

// ---- x0 = concat(query_token, zL[:, :-1]) -> f32 ----
__global__ __launch_bounds__(256) void build_x_k(const float* __restrict__ zL,
                                                 const float* __restrict__ qt,
                                                 float* __restrict__ X) {
    int idx = blockIdx.x * 256 + threadIdx.x;
    int n = idx >> 6;
    int h = (idx & 63) << 3;
    int d = (n >> 7) & 15;
    const float* src = d ? (zL + (((size_t)(n - 128)) << 9) + h) : (qt + h);
    float v[8];
    ld8f(src, v);
    st8f(X + (((size_t)n) << 9) + h, v);
}

// ---- per-row LN stats (mu, rstd); one wave per row ----
__global__ __launch_bounds__(256) void ln_stats_k(const float* __restrict__ X,
                                                  float* __restrict__ mu,
                                                  float* __restrict__ rstd) {
    int row = blockIdx.x * 4 + (threadIdx.x >> 6);
    int lane = threadIdx.x & 63;
    const float* xr = X + (((size_t)row) << 9) + (lane << 3);
    float v[8];
    ld8f(xr, v);
    float s = 0.f;
#pragma unroll
    for (int i = 0; i < 8; ++i) s += v[i];
#pragma unroll
    for (int off = 32; off; off >>= 1) s += __shfl_xor(s, off);
    float m = s * (1.0f / 512.0f);
    float q = 0.f;
#pragma unroll
    for (int i = 0; i < 8; ++i) { float d = v[i] - m; q += d * d; }
#pragma unroll
    for (int off = 32; off; off >>= 1) q += __shfl_xor(q, off);
    if (lane == 0) {
        mu[row] = m;
        rstd[row] = 1.0f / sqrtf(q * (1.0f / 512.0f) + 1e-5f);
    }
}

// ---- non-causal attention over L; 512 threads: 4 lanes per q-row (d-split) --
__global__ __launch_bounds__(512) void attn_l_k(float* __restrict__ QO,
                                                const float* __restrict__ K,
                                                const float* __restrict__ V) {
    __shared__ float ks[128][64];
    __shared__ float vs[128][64];
    const int seq = blockIdx.x, head = blockIdx.y;
    const int t = threadIdx.x;
    const size_t base = (((size_t)seq) << 16) + (head << 6);
#pragma unroll
    for (int i = 0; i < 4; ++i) {
        int slot = t + (i << 9);
        int row = slot >> 4;
        int c4 = (slot & 15) << 2;
        size_t g = base + (((size_t)row) << 9) + c4;
        *(float4*)&ks[row][c4] = *(const float4*)(K + g);
        *(float4*)&vs[row][c4] = *(const float4*)(V + g);
    }
    __syncthreads();
    const int r = t >> 2;
    const int q16 = (t & 3) << 4;
    float* qp = QO + base + (((size_t)r) << 9) + q16;
    float qr[16];
#pragma unroll
    for (int i = 0; i < 4; ++i) *(float4*)&qr[i << 2] = *(const float4*)(qp + (i << 2));
    float o[16];
#pragma unroll
    for (int d = 0; d < 16; ++d) o[d] = 0.f;
    float m = -1e30f, l = 0.f;
    for (int j = 0; j < 128; ++j) {
        const float* kp = &ks[j][q16];
        float s0 = 0.f, s1 = 0.f, s2 = 0.f, s3 = 0.f;
#pragma unroll
        for (int d = 0; d < 16; d += 4) {
            s0 = fmaf(qr[d + 0], kp[d + 0], s0);
            s1 = fmaf(qr[d + 1], kp[d + 1], s1);
            s2 = fmaf(qr[d + 2], kp[d + 2], s2);
            s3 = fmaf(qr[d + 3], kp[d + 3], s3);
        }
        float sp = (s0 + s1) + (s2 + s3);
        sp += __shfl_xor(sp, 1);
        sp += __shfl_xor(sp, 2);
        float s = sp * 0.125f;
        if (s > m) {
            float c = expf(m - s);
#pragma unroll
            for (int d = 0; d < 16; ++d) o[d] *= c;
            l *= c;
            m = s;
        }
        float w = expf(s - m);
        l += w;
        const float* vp = &vs[j][q16];
#pragma unroll
        for (int d = 0; d < 16; ++d) o[d] = fmaf(w, vp[d], o[d]);
    }
    float inv = 1.0f / l;
#pragma unroll
    for (int i = 0; i < 4; ++i)
        *(float4*)(qp + (i << 2)) = make_float4(o[i * 4] * inv, o[i * 4 + 1] * inv,
                                                o[i * 4 + 2] * inv, o[i * 4 + 3] * inv);
}

// ---- causal attention over D (1024 seqs of len 16); O over Q ----
__global__ __launch_bounds__(128) void attn_d_k(float* __restrict__ QO,
                                                const float* __restrict__ K,
                                                const float* __restrict__ V) {
    __shared__ float ks[16][512];
    __shared__ float vs[16][512];
    const int bl = blockIdx.x;
    const int b = bl >> 7, l = bl & 127;
    const int t = threadIdx.x;
    const size_t base = ((size_t)(b * 2048 + l)) << 9;
#pragma unroll
    for (int i = 0; i < 16; ++i) {
        int slot = t + (i << 7);
        int row = slot >> 7;
        int c4 = (slot & 127) << 2;
        size_t g = base + (((size_t)row) << 16) + c4;
        *(float4*)&ks[row][c4] = *(const float4*)(K + g);
        *(float4*)&vs[row][c4] = *(const float4*)(V + g);
    }
    __syncthreads();
    const int head = t >> 4, dr = t & 15;
    const int ho = head << 6;
    float qr[64];
    float* qp = QO + base + (((size_t)dr) << 16) + ho;
#pragma unroll
    for (int i = 0; i < 16; ++i) *(float4*)&qr[i << 2] = *(const float4*)(qp + (i << 2));
    float s[16];
    float m = -1e30f;
#pragma unroll
    for (int j = 0; j < 16; ++j) {
        float s0 = 0.f, s1 = 0.f, s2 = 0.f, s3 = 0.f;
#pragma unroll
        for (int d = 0; d < 64; d += 4) {
            s0 = fmaf(qr[d + 0], ks[j][ho + d + 0], s0);
            s1 = fmaf(qr[d + 1], ks[j][ho + d + 1], s1);
            s2 = fmaf(qr[d + 2], ks[j][ho + d + 2], s2);
            s3 = fmaf(qr[d + 3], ks[j][ho + d + 3], s3);
        }
        float sv = ((s0 + s1) + (s2 + s3)) * 0.125f;
        s[j] = (j <= dr) ? sv : -1e30f;
        m = fmaxf(m, s[j]);
    }
    float lsum = 0.f;
#pragma unroll
    for (int j = 0; j < 16; ++j) {
        float w = (j <= dr) ? expf(s[j] - m) : 0.f;
        s[j] = w;
        lsum += w;
    }
    float inv = 1.0f / lsum;
    float o[64];
#pragma unroll
    for (int d = 0; d < 64; ++d) o[d] = 0.f;
#pragma unroll
    for (int j = 0; j < 16; ++j) {
        float w = s[j];
#pragma unroll
        for (int d = 0; d < 64; ++d) o[d] = fmaf(w, vs[j][ho + d], o[d]);
    }
#pragma unroll
    for (int i = 0; i < 16; ++i)
        *(float4*)(qp + (i << 2)) = make_float4(o[i * 4] * inv, o[i * 4 + 1] * inv,
                                                o[i * 4 + 2] * inv, o[i * 4 + 3] * inv);
}

// ---- fused: out_xp = x; x_src(in place) = zL - x - bias_pre ----
__global__ __launch_bounds__(256) void xprior_xsrc_k(const float* __restrict__ zL,
                                                     const float* __restrict__ bias_pre,
                                                     float* __restrict__ X,
                                                     float* __restrict__ out_xp) {
    int idx = blockIdx.x * 256 + threadIdx.x;
    int h = (idx & 63) << 3;
    float z[8], p[8], x[8];
    ld8f(zL + (((size_t)idx) << 3), z);
    ld8f(bias_pre + h, p);
    float* xp = X + (((size_t)idx) << 3);
    ld8f(xp, x);
    st8f(out_xp + (((size_t)idx) << 3), x);
    float o[8];
#pragma unroll
    for (int i = 0; i < 8; ++i) o[i] = z[i] - x[i] - p[i];
    st8f(xp, o);
}

// ---- 2-way fp16 scaled split: x = h + l*2^-12 ----
__global__ __launch_bounds__(256) void split2_k(const float* __restrict__ in,
                                                _Float16* __restrict__ ph,
                                                _Float16* __restrict__ pl) {
    int idx = blockIdx.x * 256 + threadIdx.x;
    float v[8];
    ld8f(in + (((size_t)idx) << 3), v);
    _Float16 h8[8], l8[8];
#pragma unroll
    for (int i = 0; i < 8; ++i) {
        _Float16 h = (_Float16)v[i];
        float r = v[i] - (float)h;          // exact
        h8[i] = h;
        l8[i] = (_Float16)(r * LOSCALE);
    }
    *(int4*)(ph + (((size_t)idx) << 3)) = *(int4*)h8;
    *(int4*)(pl + (((size_t)idx) << 3)) = *(int4*)l8;
}

// ---- fused LN + 2-way fp16 scaled split ----
__global__ __launch_bounds__(256) void split2_ln_k(const float* __restrict__ X,
                                                   const float* __restrict__ mu,
                                                   const float* __restrict__ rstd,
                                                   const float* __restrict__ gamma,
                                                   const float* __restrict__ beta,
                                                   _Float16* __restrict__ ph,
                                                   _Float16* __restrict__ pl) {
    int idx = blockIdx.x * 256 + threadIdx.x;
    int row = idx >> 6;
    int h = (idx & 63) << 3;
    float v[8], gv[8], be[8];
    ld8f(X + (((size_t)idx) << 3), v);
    ld8f(gamma + h, gv);
    ld8f(beta + h, be);
    float m = mu[row], rs = rstd[row];
    _Float16 h8[8], l8[8];
#pragma unroll
    for (int i = 0; i < 8; ++i) {
        float y = (v[i] - m) * rs * gv[i] + be[i];
        _Float16 hh = (_Float16)y;
        float r = y - (float)hh;
        h8[i] = hh;
        l8[i] = (_Float16)(r * LOSCALE);
    }
    *(int4*)(ph + (((size_t)idx) << 3)) = *(int4*)h8;
    *(int4*)(pl + (((size_t)idx) << 3)) = *(int4*)l8;
}

// ---- 3-pass split-fp16 MFMA NT GEMM, 32x32x16, 128x64 tile -----------------
// 4 waves, each owns a 64x32 output tile (mf=2, nf=1): acc regs halved to
// 64/thread (2 tiles x (acc1,acc2) x 16) so waves/SIMD goes 1 -> 3 and the
// staging latency hides behind TLP (round-12 post-mortem: 1 wave/SIMD was
// the bottleneck, not LDS banks).
// C/D layout per m74/m101: col=lane&31, row=(reg&3)+8*(reg>>2)+4*(lane>>5).
#define LDT 34
template<bool ADD_C, bool BIAS>
__global__ __launch_bounds__(256) void gemm_f16_k(
        const _Float16* __restrict__ Xh, const _Float16* __restrict__ Xl,
        const _Float16* __restrict__ Wh, const _Float16* __restrict__ Wl,
        const float* __restrict__ bias, float* __restrict__ Cout, int ldc) {
    __shared__ _Float16 Ah[128][LDT], Al[128][LDT];
    __shared__ _Float16 Bh[64][LDT],  Bl[64][LDT];
    const int tid = threadIdx.x;
    const int bm = blockIdx.y << 7;      // 128-row tile
    const int bn = blockIdx.x << 6;      // 64-col tile
    const int w = tid >> 6, lane = tid & 63;
    const int wr = w >> 1, wc = w & 1;   // wave tile: rows wr*64.., cols wc*32..
    const int l31 = lane & 31, hh = lane >> 5;
    f32x16 acc1[2], acc2[2];
#pragma unroll
    for (int i = 0; i < 2; ++i)
#pragma unroll
        for (int r = 0; r < 16; ++r) { acc1[i][r] = 0.f; acc2[i][r] = 0.f; }

    for (int k0 = 0; k0 < HDIM; k0 += 32) {
        __syncthreads();
#pragma unroll
        for (int i = 0; i < 2; ++i) {   // A: 128 rows x 32 halves
            int s = tid + (i << 8);
            int row = s >> 2, kg = (s & 3) << 3;
            size_t ga = (size_t)(bm + row) * HDIM + k0 + kg;
            *(int4*)&Ah[row][kg] = *(const int4*)(Xh + ga);
            *(int4*)&Al[row][kg] = *(const int4*)(Xl + ga);
        }
        {                               // B: 64 rows x 32 halves
            int row = tid >> 2, kg = (tid & 3) << 3;
            size_t gb = (size_t)(bn + row) * HDIM + k0 + kg;
            *(int4*)&Bh[row][kg] = *(const int4*)(Wh + gb);
            *(int4*)&Bl[row][kg] = *(const int4*)(Wl + gb);
        }
        __syncthreads();
#pragma unroll
        for (int kh = 0; kh < 2; ++kh) {
            const int ko = (kh << 4) + (hh << 3);   // k offset (halves)
            f16x8 fah[2], fal[2];
#pragma unroll
            for (int mf = 0; mf < 2; ++mf) {
                int ar = (wr << 6) + (mf << 5) + l31;
                fah[mf] = *(const f16x8*)&Ah[ar][ko];
                fal[mf] = *(const f16x8*)&Al[ar][ko];
            }
            int bc_ = (wc << 5) + l31;
            f16x8 bh = *(const f16x8*)&Bh[bc_][ko];
            f16x8 bl = *(const f16x8*)&Bl[bc_][ko];
#pragma unroll
            for (int mf = 0; mf < 2; ++mf) {
                acc1[mf] = __builtin_amdgcn_mfma_f32_32x32x16_f16(fah[mf], bh, acc1[mf], 0, 0, 0);
                acc2[mf] = __builtin_amdgcn_mfma_f32_32x32x16_f16(fah[mf], bl, acc2[mf], 0, 0, 0);
                acc2[mf] = __builtin_amdgcn_mfma_f32_32x32x16_f16(fal[mf], bh, acc2[mf], 0, 0, 0);
            }
        }
    }
    const int col = bn + (wc << 5) + l31;
    const float badd = BIAS ? bias[col] : 0.f;
#pragma unroll
    for (int mf = 0; mf < 2; ++mf) {
#pragma unroll
        for (int r = 0; r < 16; ++r) {
            int row = bm + (wr << 6) + (mf << 5) + (r & 3) + ((r >> 2) << 3) + (hh << 2);
            float* cp = Cout + (size_t)row * ldc + col;
            float val = acc1[mf][r] + acc2[mf][r] * LOINV + badd;
            if (ADD_C) val += *cp;
            *cp = val;
        }
    }
}

// ---- per-row top-64: relu + exact radix select (early-exit) + scatter ----
__global__ __launch_bounds__(256) void topk_k(const float* __restrict__ logits,
                                              float* __restrict__ out) {
    const int row = blockIdx.x;
    const float* lr = logits + (((size_t)row) << 12);
    const int t = threadIdx.x;
    float v[16]; uint32_t u[16];
#pragma unroll
    for (int i = 0; i < 16; ++i) {
        float x = fmaxf(lr[t + (i << 8)], 0.f);
        v[i] = x;
        u[i] = __float_as_uint(x);
    }
    __shared__ int red[4];
    __shared__ unsigned long long bits[64];
    __shared__ int s_cut;
    uint32_t prefix = 0;
    bool exact = false;
    for (int bit = 30; bit >= 0; --bit) {
        uint32_t c = prefix | (1u << bit);
        int cnt = 0;
#pragma unroll
        for (int i = 0; i < 16; ++i) cnt += (u[i] >= c) ? 1 : 0;
#pragma unroll
        for (int off = 32; off; off >>= 1) cnt += __shfl_xor(cnt, off);
        if ((t & 63) == 0) red[t >> 6] = cnt;
        __syncthreads();
        int total = red[0] + red[1] + red[2] + red[3];
        __syncthreads();
        if (total >= 64) prefix = c;
        if (total == 64) { exact = true; break; }   // block-uniform
    }
    float* orow = out + (((size_t)row) << 12);
    if (exact) {
#pragma unroll
        for (int i = 0; i < 16; ++i) {
            int col = t + (i << 8);
            orow[col] = (u[i] >= prefix) ? v[i] : 0.f;
        }
        return;
    }
    const uint32_t T64 = prefix;
    int cg = 0;
#pragma unroll
    for (int i = 0; i < 16; ++i) cg += (u[i] > T64) ? 1 : 0;
#pragma unroll
    for (int off = 32; off; off >>= 1) cg += __shfl_xor(cg, off);
    if ((t & 63) == 0) red[t >> 6] = cg;
    __syncthreads();
    const int ngt = red[0] + red[1] + red[2] + red[3];
    int cut = -1;
    if (T64 != 0u) {
        const int r = 64 - ngt;
        if (t < 64) bits[t] = 0ull;
        __syncthreads();
#pragma unroll
        for (int i = 0; i < 16; ++i) {
            if (u[i] == T64) {
                int col = t + (i << 8);
                atomicOr(&bits[col >> 6], 1ull << (col & 63));
            }
        }
        __syncthreads();
        if (t == 0) {
            int need = r, cs = FDIM - 1;
            for (int wd = 0; wd < 64; ++wd) {
                int pc = __popcll(bits[wd]);
                if (need <= pc) {
                    unsigned long long bb = bits[wd];
                    for (int q = 1; q < need; ++q) bb &= bb - 1;
                    cs = (wd << 6) + (__ffsll(bb) - 1);
                    break;
                }
                need -= pc;
            }
            s_cut = cs;
        }
        __syncthreads();
        cut = s_cut;
    }
#pragma unroll
    for (int i = 0; i < 16; ++i) {
        int col = t + (i << 8);
        bool keep = (u[i] > T64) || (T64 != 0u && u[i] == T64 && col <= cut);
        orow[col] = keep ? v[i] : 0.f;
    }
}

extern "C" void kernel_launch(void* const* d_in, const int* in_sizes, int n_in,
                              void* d_out, int out_size, void* d_ws, size_t ws_size,
                              hipStream_t stream) {
    const float* zL      = (const float*)d_in[0];
    const float* gamma_l = (const float*)d_in[5];
    const float* beta_l  = (const float*)d_in[6];
    const float* gamma_d = (const float*)d_in[11];
    const float* beta_d  = (const float*)d_in[12];
    const float* dict_e  = (const float*)d_in[13];
    const float* bias_pre= (const float*)d_in[14];
    const float* bias_enc= (const float*)d_in[15];
    const float* qt      = (const float*)d_in[16];
    const float* wproj[8] = { (const float*)d_in[1], (const float*)d_in[2],
                              (const float*)d_in[3], (const float*)d_in[4],
                              (const float*)d_in[7], (const float*)d_in[8],
                              (const float*)d_in[9], (const float*)d_in[10] };

    float* out_z  = (float*)d_out;
    float* out_xp = out_z + (size_t)NTOK * FDIM;

    const size_t NHf = (size_t)NTOK * HDIM;
    float* B0 = (float*)d_out;         // residual X -> x_prior -> x_src
    float* B1 = B0 + NHf;              // Q / attn out
    float* B2 = B1 + NHf;              // K
    float* B3 = B2 + NHf;              // V

    float* wsf    = (float*)d_ws;
    float* mu     = wsf + 64;
    float* rstd   = mu + NTOK;
    float* logits = rstd + NTOK;       // crows*4096 f32

    const size_t dictE = (size_t)FDIM * HDIM;   // 2.1M
    const size_t WE    = (size_t)HDIM * HDIM;   // 262144

    int crows = NTOK;                  // single dict dispatch if ws allows
    const size_t mfmaFixedB = (64 + 2 * (size_t)NTOK) * sizeof(float)
                            + (2 * dictE + 16 * WE + 2 * NHf) * sizeof(_Float16);
    while (crows > 128 &&
           mfmaFixedB + (size_t)crows * FDIM * sizeof(float) > ws_size) crows >>= 1;
    // this path requires the fp16 buffers to fit; fall back to tiny chunks otherwise
    const bool ok = mfmaFixedB + (size_t)128 * FDIM * sizeof(float) <= ws_size;

    const dim3 blk256(256), blk128(128), blk512(512);
    const dim3 gElem(4096);                       // NTOK*512/8/256
    const dim3 gProjM(HDIM / 64, NTOK / 128);     // (8, 128)

    if (ok) {
        _Float16* dh = (_Float16*)(logits + (size_t)crows * FDIM);
        _Float16* dl = dh + dictE;
        _Float16* wsp = dh + 2 * dictE;          // 8 weights x 2 splits x WE
        _Float16* xh = wsp + 16 * WE;
        _Float16* xl = xh + NHf;
        _Float16* wh[8], *wl[8];
        for (int i = 0; i < 8; ++i) {
            wh[i] = wsp + (size_t)i * 2 * WE;
            wl[i] = wh[i] + WE;
        }

        for (int i = 0; i < 8; ++i)
            split2_k<<<dim3(WE / 8 / 256), blk256, 0, stream>>>(wproj[i], wh[i], wl[i]);
        split2_k<<<dim3(dictE / 8 / 256), blk256, 0, stream>>>(dict_e, dh, dl);

        build_x_k<<<gElem, blk256, 0, stream>>>(zL, qt, B0);

        // ---- layer attention block ----
        ln_stats_k<<<dim3(NTOK / 4), blk256, 0, stream>>>(B0, mu, rstd);
        split2_ln_k<<<gElem, blk256, 0, stream>>>(B0, mu, rstd, gamma_l, beta_l, xh, xl);
        gemm_f16_k<false, false><<<gProjM, blk256, 0, stream>>>(xh, xl, wh[0], wl[0], nullptr, B1, HDIM);
        gemm_f16_k<false, false><<<gProjM, blk256, 0, stream>>>(xh, xl, wh[1], wl[1], nullptr, B2, HDIM);
        gemm_f16_k<false, false><<<gProjM, blk256, 0, stream>>>(xh, xl, wh[2], wl[2], nullptr, B3, HDIM);
        attn_l_k<<<dim3(128, NHEAD), blk512, 0, stream>>>(B1, B2, B3);
        split2_k<<<gElem, blk256, 0, stream>>>(B1, xh, xl);
        gemm_f16_k<true, false><<<gProjM, blk256, 0, stream>>>(xh, xl, wh[3], wl[3], nullptr, B0, HDIM);

        // ---- depth attention block ----
        ln_stats_k<<<dim3(NTOK / 4), blk256, 0, stream>>>(B0, mu, rstd);
        split2_ln_k<<<gElem, blk256, 0, stream>>>(B0, mu, rstd, gamma_d, beta_d, xh, xl);
        gemm_f16_k<false, false><<<gProjM, blk256, 0, stream>>>(xh, xl, wh[4], wl[4], nullptr, B1, HDIM);
        gemm_f16_k<false, false><<<gProjM, blk256, 0, stream>>>(xh, xl, wh[5], wl[5], nullptr, B2, HDIM);
        gemm_f16_k<false, false><<<gProjM, blk256, 0, stream>>>(xh, xl, wh[6], wl[6], nullptr, B3, HDIM);
        attn_d_k<<<dim3(1024), blk128, 0, stream>>>(B1, B2, B3);
        split2_k<<<gElem, blk256, 0, stream>>>(B1, xh, xl);
        gemm_f16_k<true, false><<<gProjM, blk256, 0, stream>>>(xh, xl, wh[7], wl[7], nullptr, B0, HDIM);

        // ---- x_prior out + x_src + one-shot split ----
        xprior_xsrc_k<<<gElem, blk256, 0, stream>>>(zL, bias_pre, B0, out_xp);
        split2_k<<<gElem, blk256, 0, stream>>>(B0, xh, xl);

        const dim3 gDict(FDIM / 64, crows / 128);   // (64, crows/128)
        for (int c0 = 0; c0 < NTOK; c0 += crows) {
            gemm_f16_k<false, true><<<gDict, blk256, 0, stream>>>(
                xh + (size_t)c0 * HDIM, xl + (size_t)c0 * HDIM,
                dh, dl, bias_enc, logits, FDIM);
            topk_k<<<dim3(crows), blk256, 0, stream>>>(logits, out_z + (size_t)c0 * FDIM);
        }
    } else {
        // ---- minimal-workspace fallback: per-chunk fp16 splits ----
        int cr = 2048;
        const size_t fixedB = (64 + 2 * (size_t)NTOK) * sizeof(float) + dictE * 2 * sizeof(_Float16);
        while (cr > 128 &&
               fixedB + (size_t)cr * FDIM * sizeof(float) + ((size_t)cr * HDIM + 16 * WE) * 2 * sizeof(_Float16) > ws_size)
            cr >>= 1;
        _Float16* dh = (_Float16*)(logits + (size_t)cr * FDIM);
        _Float16* dl = dh + dictE;
        _Float16* xh = dl + dictE;
        _Float16* xl = xh + (size_t)cr * HDIM;
        _Float16* wh = xl + (size_t)cr * HDIM;     // one weight pair at a time
        _Float16* wlo = wh + WE;

        build_x_k<<<gElem, blk256, 0, stream>>>(zL, qt, B0);

        ln_stats_k<<<dim3(NTOK / 4), blk256, 0, stream>>>(B0, mu, rstd);
        for (int i = 0; i < 3; ++i) {
            // Q/K/V proj via chunked A-splits
            split2_k<<<dim3(WE / 8 / 256), blk256, 0, stream>>>(wproj[i], wh, wlo);
            float* dst = (i == 0) ? B1 : (i == 1) ? B2 : B3;
            for (int c0 = 0; c0 < NTOK; c0 += cr) {
                split2_ln_k<<<dim3(cr * HDIM / 8 / 256), blk256, 0, stream>>>(
                    B0 + (size_t)c0 * HDIM, mu + c0, rstd + c0, gamma_l, beta_l, xh, xl);
                gemm_f16_k<false, false><<<dim3(HDIM / 64, cr / 128), blk256, 0, stream>>>(
                    xh, xl, wh, wlo, nullptr, dst + (size_t)c0 * HDIM, HDIM);
            }
        }
        attn_l_k<<<dim3(128, NHEAD), blk512, 0, stream>>>(B1, B2, B3);
        split2_k<<<dim3(WE / 8 / 256), blk256, 0, stream>>>(wproj[3], wh, wlo);
        for (int c0 = 0; c0 < NTOK; c0 += cr) {
            split2_k<<<dim3(cr * HDIM / 8 / 256), blk256, 0, stream>>>(B1 + (size_t)c0 * HDIM, xh, xl);
            gemm_f16_k<true, false><<<dim3(HDIM / 64, cr / 128), blk256, 0, stream>>>(
                xh, xl, wh, wlo, nullptr, B0 + (size_t)c0 * HDIM, HDIM);
        }
        ln_stats_k<<<dim3(NTOK / 4), blk256, 0, stream>>>(B0, mu, rstd);
        for (int i = 4; i < 7; ++i) {
            split2_k<<<dim3(WE / 8 / 256), blk256, 0, stream>>>(wproj[i], wh, wlo);
            float* dst = (i == 4) ? B1 : (i == 5) ? B2 : B3;
            for (int c0 = 0; c0 < NTOK; c0 += cr) {
                split2_ln_k<<<dim3(cr * HDIM / 8 / 256), blk256, 0, stream>>>(
                    B0 + (size_t)c0 * HDIM, mu + c0, rstd + c0, gamma_d, beta_d, xh, xl);
                gemm_f16_k<false, false><<<dim3(HDIM / 64, cr / 128), blk256, 0, stream>>>(
                    xh, xl, wh, wlo, nullptr, dst + (size_t)c0 * HDIM, HDIM);
            }
        }
        attn_d_k<<<dim3(1024), blk128, 0, stream>>>(B1, B2, B3);
        split2_k<<<dim3(WE / 8 / 256), blk256, 0, stream>>>(wproj[7], wh, wlo);
        for (int c0 = 0; c0 < NTOK; c0 += cr) {
            split2_k<<<dim3(cr * HDIM / 8 / 256), blk256, 0, stream>>>(B1 + (size_t)c0 * HDIM, xh, xl);
            gemm_f16_k<true, false><<<dim3(HDIM / 64, cr / 128), blk256, 0, stream>>>(
                xh, xl, wh, wlo, nullptr, B0 + (size_t)c0 * HDIM, HDIM);
        }
        xprior_xsrc_k<<<gElem, blk256, 0, stream>>>(zL, bias_pre, B0, out_xp);
        split2_k<<<dim3(dictE / 8 / 256), blk256, 0, stream>>>(dict_e, dh, dl);
        for (int c0 = NTOK - cr; c0 >= 0; c0 -= cr) {
            split2_k<<<dim3(cr * HDIM / 8 / 256), blk256, 0, stream>>>(B0 + (size_t)c0 * HDIM, xh, xl);
            gemm_f16_k<false, true><<<dim3(FDIM / 64, cr / 128), blk256, 0, stream>>>(
                xh, xl, dh, dl, bias_enc, logits, FDIM);
            topk_k<<<dim3(cr), blk256, 0, stream>>>(logits, out_z + (size_t)c0 * FDIM);
        }
    }
}